// Round 1
// baseline (9180.536 us; speedup 1.0000x reference)
//
#include <hip/hip_runtime.h>
#include <hip/hip_bf16.h>

// GRU: B=32, T=16384, H=64, CIN=COUT=1.
// d_out = [ out (B*T floats) | states (B*T*H floats) ], fp32.
//
// Strategy: one workgroup per batch element (32 WGs, 192 threads = 3 waves).
// Sequential scan over T with ONE barrier per step:
//   - thread g holds W_hh row g (64 VGPRs); per step computes gh[g] = b_hh[g] + W_hh[g,:]·h
//     reading h from its wave's PRIVATE LDS copy (same-wave write->read, no barrier).
//   - gh exchanged via double-buffered LDS; after the barrier EVERY wave redundantly
//     computes the h-update for its lane (cheaper than a second barrier).
//   - x staged in LDS chunks (4KB / 1024 steps); states buffered in a 16KB LDS chunk,
//     flushed every 64 steps (amortizes the vmcnt(0) drain at barriers to 1/64 steps).
// Head computed by a separate memory-bound kernel.

#define Bv   32
#define Tv   16384
#define Hv   64
#define Gv   192      // 3*H gate rows
#define XCH  1024     // x chunk (floats)
#define SCH  64       // states chunk (steps)

__global__ __launch_bounds__(Gv, 1) void gru_scan(
    const float* __restrict__ x,      // [B,T]
    const float* __restrict__ W_ih,   // [192] (CIN=1)
    const float* __restrict__ W_hh,   // [192,64]
    const float* __restrict__ b_ih,   // [192]
    const float* __restrict__ b_hh,   // [192]
    float* __restrict__ states)       // [B,T,64]
{
    const int b    = blockIdx.x;
    const int g    = threadIdx.x;   // gate row 0..191
    const int wave = g >> 6;
    const int lane = g & 63;        // hidden unit this thread updates

    __shared__ float xs[XCH];          // 4 KB   x chunk
    __shared__ float hb[3][Hv];        // 768 B  per-wave private h copy
    __shared__ float ghs[2][Gv];       // 1.5 KB double-buffered gate pre-activations
    __shared__ float sc[SCH * Hv];     // 16 KB  states chunk

    const float* xb = x + (size_t)b * Tv;
    float*       sb = states + (size_t)b * Tv * Hv;

    // W_hh row g -> registers (fully unrolled use keeps it in VGPRs)
    float w[Hv];
#pragma unroll
    for (int k = 0; k < Hv; k += 4) {
        const float4 v = *reinterpret_cast<const float4*>(W_hh + (size_t)g * Hv + k);
        w[k+0] = v.x; w[k+1] = v.y; w[k+2] = v.z; w[k+3] = v.w;
    }
    const float bhh_g = b_hh[g];

    // update-phase constants (per lane; identical across the 3 waves)
    const float wih_r = W_ih[lane];
    const float wih_z = W_ih[64  + lane];
    const float wih_n = W_ih[128 + lane];
    const float bih_r = b_ih[lane];
    const float bih_z = b_ih[64  + lane];
    const float bih_n = b_ih[128 + lane];

    // h0 = 0 in this wave's private copy (same-wave visibility, no barrier needed)
    hb[wave][lane] = 0.0f;
    float h_prev = 0.0f;

    for (int t0 = 0; t0 < Tv; t0 += SCH) {
        if ((t0 & (XCH - 1)) == 0) {
            __syncthreads();                       // prior xs readers done
            for (int i = g; i < XCH; i += Gv) xs[i] = xb[t0 + i];
            __syncthreads();
        }

        for (int tt = 0; tt < SCH; ++tt) {
            const int t  = t0 + tt;
            const int pb = t & 1;

            // ---- matvec: gh[g] = b_hh[g] + W_hh[g,:] . h  (own-wave h copy) ----
            float acc = bhh_g;
            const float4* hv = reinterpret_cast<const float4*>(hb[wave]);
#pragma unroll
            for (int k4 = 0; k4 < Hv / 4; ++k4) {
                const float4 hh = hv[k4];
                acc = fmaf(w[4*k4+0], hh.x, acc);
                acc = fmaf(w[4*k4+1], hh.y, acc);
                acc = fmaf(w[4*k4+2], hh.z, acc);
                acc = fmaf(w[4*k4+3], hh.w, acc);
            }
            ghs[pb][g] = acc;
            __syncthreads();   // the only barrier per step

            // ---- redundant h-update on all 3 waves (lane = hidden unit) ----
            const float xt = xs[t & (XCH - 1)];
            const float gr = ghs[pb][lane];
            const float gz = ghs[pb][64  + lane];
            const float gn = ghs[pb][128 + lane];

            const float r = 1.0f / (1.0f + __expf(-(fmaf(xt, wih_r, bih_r) + gr)));
            const float z = 1.0f / (1.0f + __expf(-(fmaf(xt, wih_z, bih_z) + gz)));
            const float a = fmaf(xt, wih_n, bih_n) + r * gn;
            const float e = __expf(2.0f * a);            // tanh(a) = 1 - 2/(e+1)
            const float n = 1.0f - 2.0f / (e + 1.0f);
            const float hn = fmaf(z, h_prev - n, n);     // (1-z)*n + z*h
            h_prev = hn;
            hb[wave][lane] = hn;                          // own-wave copy; no barrier
            if (wave == 0) sc[tt * Hv + lane] = hn;       // buffer states in LDS
        }

        __syncthreads();   // sc complete & visible to all waves
        {   // flush 64 steps of states: 16KB, float4, all 192 threads
            const float4* s4 = reinterpret_cast<const float4*>(sc);
            float4*       d4 = reinterpret_cast<float4*>(sb + (size_t)t0 * Hv);
            for (int i = g; i < (SCH * Hv) / 4; i += Gv) d4[i] = s4[i];
        }
        // no barrier needed: next chunk's sc writes happen only after the next
        // step's __syncthreads(), by which time all flush reads are complete.
    }
}

// out[i] = states[i,:] . W_out + b_out + x[i],  i in [0, B*T)
__global__ __launch_bounds__(256) void gru_head(
    const float* __restrict__ x,
    const float* __restrict__ states,
    const float* __restrict__ W_out,   // [64]
    const float* __restrict__ b_out,   // [1]
    float* __restrict__ out)
{
    __shared__ float wsm[Hv];
    if (threadIdx.x < Hv) wsm[threadIdx.x] = W_out[threadIdx.x];
    __syncthreads();

    const int i = blockIdx.x * blockDim.x + threadIdx.x;
    if (i >= Bv * Tv) return;

    const float4* s4 = reinterpret_cast<const float4*>(states + (size_t)i * Hv);
    float acc = 0.0f;
#pragma unroll
    for (int k = 0; k < Hv / 4; ++k) {
        const float4 v = s4[k];
        acc = fmaf(v.x, wsm[4*k+0], acc);
        acc = fmaf(v.y, wsm[4*k+1], acc);
        acc = fmaf(v.z, wsm[4*k+2], acc);
        acc = fmaf(v.w, wsm[4*k+3], acc);
    }
    out[i] = acc + b_out[0] + x[i];
}

extern "C" void kernel_launch(void* const* d_in, const int* in_sizes, int n_in,
                              void* d_out, int out_size, void* d_ws, size_t ws_size,
                              hipStream_t stream) {
    const float* x     = (const float*)d_in[0];   // [B,T,1]
    const float* W_ih  = (const float*)d_in[1];   // [192,1]
    const float* W_hh  = (const float*)d_in[2];   // [192,64]
    const float* b_ih  = (const float*)d_in[3];   // [192]
    const float* b_hh  = (const float*)d_in[4];   // [192]
    const float* W_out = (const float*)d_in[5];   // [1,64]
    const float* b_out = (const float*)d_in[6];   // [1]

    float* out    = (float*)d_out;                // [B*T]
    float* states = out + (size_t)Bv * Tv;        // [B*T*H]

    gru_scan<<<Bv, Gv, 0, stream>>>(x, W_ih, W_hh, b_ih, b_hh, states);
    gru_head<<<(Bv * Tv + 255) / 256, 256, 0, stream>>>(x, states, W_out, b_out, out);
}

// Round 3
// 8446.745 us; speedup vs baseline: 1.0869x; 1.0869x over previous
//
#include <hip/hip_runtime.h>
#include <hip/hip_bf16.h>

// GRU: B=32, T=16384, H=64, CIN=COUT=1.
// d_out = [ out (B*T floats) | states (B*T*H floats) ], fp32.
//
// One workgroup per batch element (32 WGs, 192 threads = 3 waves), one barrier
// per step. R3 = R2 with the DOT4 macro replaced by an inline function (the
// macro param `w` was being substituted into the `.w` member access).
//   - W_hh row held in 16 NAMED float4 registers (R1's w[64] array was demoted
//     to scratch: VGPR_Count=52 -> per-step scratch reloads on the serial path).
//   - 4 independent accumulators break the 64-deep fmaf dependency chain.
//   - x-dependent gate inputs hoisted before the barrier (off the critical path).

#define Bv   32
#define Tv   16384
#define Hv   64
#define Gv   192      // 3*H gate rows
#define XCH  1024     // x chunk (floats)
#define SCH  64       // states chunk (steps)

__device__ __forceinline__ float dot4(float acc, const float4 a, const float4 b) {
    return fmaf(a.x, b.x, fmaf(a.y, b.y, fmaf(a.z, b.z, fmaf(a.w, b.w, acc))));
}

__global__ __launch_bounds__(Gv, 1) void gru_scan(
    const float* __restrict__ x,      // [B,T]
    const float* __restrict__ W_ih,   // [192] (CIN=1)
    const float* __restrict__ W_hh,   // [192,64]
    const float* __restrict__ b_ih,   // [192]
    const float* __restrict__ b_hh,   // [192]
    float* __restrict__ states)       // [B,T,64]
{
    const int b    = blockIdx.x;
    const int g    = threadIdx.x;   // gate row 0..191
    const int wave = g >> 6;
    const int lane = g & 63;        // hidden unit this thread updates

    __shared__ float xs[XCH];          // 4 KB   x chunk
    __shared__ float hb[3][Hv];        // 768 B  per-wave private h copy
    __shared__ float ghs[2][Gv];       // 1.5 KB double-buffered gate pre-activations
    __shared__ float sc[SCH * Hv];     // 16 KB  states chunk

    const float* xb = x + (size_t)b * Tv;
    float*       sb = states + (size_t)b * Tv * Hv;

    // W_hh row g -> 16 named float4 registers (guaranteed VGPR-resident)
    const float4* Wv = reinterpret_cast<const float4*>(W_hh + (size_t)g * Hv);
    const float4 w0  = Wv[0],  w1  = Wv[1],  w2  = Wv[2],  w3  = Wv[3];
    const float4 w4  = Wv[4],  w5  = Wv[5],  w6  = Wv[6],  w7  = Wv[7];
    const float4 w8  = Wv[8],  w9  = Wv[9],  w10 = Wv[10], w11 = Wv[11];
    const float4 w12 = Wv[12], w13 = Wv[13], w14 = Wv[14], w15 = Wv[15];
    const float bhh_g = b_hh[g];

    // update-phase constants (per lane; identical across the 3 waves)
    const float wih_r = W_ih[lane];
    const float wih_z = W_ih[64  + lane];
    const float wih_n = W_ih[128 + lane];
    const float bih_r = b_ih[lane];
    const float bih_z = b_ih[64  + lane];
    const float bih_n = b_ih[128 + lane];

    // h0 = 0 in this wave's private copy (same-wave visibility, no barrier needed)
    hb[wave][lane] = 0.0f;
    float h_prev = 0.0f;

    for (int t0 = 0; t0 < Tv; t0 += SCH) {
        if ((t0 & (XCH - 1)) == 0) {
            __syncthreads();                       // prior xs readers done
            for (int i = g; i < XCH; i += Gv) xs[i] = xb[t0 + i];
            __syncthreads();
        }

        for (int tt = 0; tt < SCH; ++tt) {
            const int t  = t0 + tt;
            const int pb = t & 1;

            // ---- x-dependent gate inputs: off the post-barrier critical path ----
            const float xt = xs[t & (XCH - 1)];
            const float ir = fmaf(xt, wih_r, bih_r);
            const float iz = fmaf(xt, wih_z, bih_z);
            const float in_ = fmaf(xt, wih_n, bih_n);

            // ---- matvec: gh[g] = b_hh[g] + W_hh[g,:] . h  (own-wave h copy) ----
            const float4* hv = reinterpret_cast<const float4*>(hb[wave]);
            const float4 h0  = hv[0],  h1  = hv[1],  h2  = hv[2],  h3  = hv[3];
            const float4 h4  = hv[4],  h5  = hv[5],  h6  = hv[6],  h7  = hv[7];
            const float4 h8  = hv[8],  h9  = hv[9],  h10 = hv[10], h11 = hv[11];
            const float4 h12 = hv[12], h13 = hv[13], h14 = hv[14], h15 = hv[15];

            float a0 = bhh_g, a1 = 0.0f, a2 = 0.0f, a3 = 0.0f;  // 4 indep chains
            a0 = dot4(a0, w0,  h0);  a1 = dot4(a1, w1,  h1);
            a2 = dot4(a2, w2,  h2);  a3 = dot4(a3, w3,  h3);
            a0 = dot4(a0, w4,  h4);  a1 = dot4(a1, w5,  h5);
            a2 = dot4(a2, w6,  h6);  a3 = dot4(a3, w7,  h7);
            a0 = dot4(a0, w8,  h8);  a1 = dot4(a1, w9,  h9);
            a2 = dot4(a2, w10, h10); a3 = dot4(a3, w11, h11);
            a0 = dot4(a0, w12, h12); a1 = dot4(a1, w13, h13);
            a2 = dot4(a2, w14, h14); a3 = dot4(a3, w15, h15);
            ghs[pb][g] = (a0 + a1) + (a2 + a3);
            __syncthreads();   // the only barrier per step

            // ---- redundant h-update on all 3 waves (lane = hidden unit) ----
            const float gr = ghs[pb][lane];
            const float gz = ghs[pb][64  + lane];
            const float gn = ghs[pb][128 + lane];

            const float r = 1.0f / (1.0f + __expf(-(ir + gr)));
            const float z = 1.0f / (1.0f + __expf(-(iz + gz)));
            const float a = in_ + r * gn;
            const float e = __expf(2.0f * a);            // tanh(a) = 1 - 2/(e+1)
            const float n = 1.0f - 2.0f / (e + 1.0f);
            const float hn = fmaf(z, h_prev - n, n);     // (1-z)*n + z*h
            h_prev = hn;
            hb[wave][lane] = hn;                          // own-wave copy; no barrier
            if (wave == 0) sc[tt * Hv + lane] = hn;       // buffer states in LDS
        }

        __syncthreads();   // sc complete & visible to all waves
        {   // flush 64 steps of states: 16KB, float4, all 192 threads
            const float4* s4 = reinterpret_cast<const float4*>(sc);
            float4*       d4 = reinterpret_cast<float4*>(sb + (size_t)t0 * Hv);
            for (int i = g; i < (SCH * Hv) / 4; i += Gv) d4[i] = s4[i];
        }
        // no barrier needed: next chunk's sc writes happen only after the next
        // step's __syncthreads(), by which time all flush reads are complete.
    }
}

// out[i] = states[i,:] . W_out + b_out + x[i],  i in [0, B*T)
__global__ __launch_bounds__(256) void gru_head(
    const float* __restrict__ x,
    const float* __restrict__ states,
    const float* __restrict__ W_out,   // [64]
    const float* __restrict__ b_out,   // [1]
    float* __restrict__ out)
{
    __shared__ float wsm[Hv];
    if (threadIdx.x < Hv) wsm[threadIdx.x] = W_out[threadIdx.x];
    __syncthreads();

    const int i = blockIdx.x * blockDim.x + threadIdx.x;
    if (i >= Bv * Tv) return;

    const float4* s4 = reinterpret_cast<const float4*>(states + (size_t)i * Hv);
    float acc = 0.0f;
#pragma unroll
    for (int k = 0; k < Hv / 4; ++k) {
        const float4 v = s4[k];
        acc = fmaf(v.x, wsm[4*k+0], acc);
        acc = fmaf(v.y, wsm[4*k+1], acc);
        acc = fmaf(v.z, wsm[4*k+2], acc);
        acc = fmaf(v.w, wsm[4*k+3], acc);
    }
    out[i] = acc + b_out[0] + x[i];
}

extern "C" void kernel_launch(void* const* d_in, const int* in_sizes, int n_in,
                              void* d_out, int out_size, void* d_ws, size_t ws_size,
                              hipStream_t stream) {
    const float* x     = (const float*)d_in[0];   // [B,T,1]
    const float* W_ih  = (const float*)d_in[1];   // [192,1]
    const float* W_hh  = (const float*)d_in[2];   // [192,64]
    const float* b_ih  = (const float*)d_in[3];   // [192]
    const float* b_hh  = (const float*)d_in[4];   // [192]
    const float* W_out = (const float*)d_in[5];   // [1,64]
    const float* b_out = (const float*)d_in[6];   // [1]

    float* out    = (float*)d_out;                // [B*T]
    float* states = out + (size_t)Bv * Tv;        // [B*T*H]

    gru_scan<<<Bv, Gv, 0, stream>>>(x, W_ih, W_hh, b_ih, b_hh, states);
    gru_head<<<(Bv * Tv + 255) / 256, 256, 0, stream>>>(x, states, W_out, b_out, out);
}